// Round 4
// baseline (549.572 us; speedup 1.0000x reference)
//
#include <hip/hip_runtime.h>

#define BLOCKS 2048
#define TPB 256
#define RED_TPB 1024
#define RED_SLICES (RED_TPB / 64)

// Main pass: per-row hamming-distance histogram + per-column BCE partial sums.
// One wave handles a SUPERCHUNK = 16 rows = 1024 floats = 4KB per array per
// iteration: 8 dwordx4 wave-loads issued back-to-back before any use.
//
// Per 4-row chunk: lane k holds floats [4*(k&15) .. +3] of row (k>>4).
// (p != g) compares double as wave ballots; row hamming distance = popcount of
// the row's 16-bit slice of the 4 ballot masks.
//
// BCE on exact {0,1} inputs: loss = ln2 + p*((1-g) + log1p(e^-1) - ln2).
// ln2*N is added per column at finalize.
//
// NO global atomics: each block scatters its 64 hist counts + 64 col sums to a
// private slot in d_ws; a one-block reducer folds 2048 slots -> scalar.
__global__ __launch_bounds__(TPB) void hwbce_main(
    const float4* __restrict__ pred, const float4* __restrict__ gt,
    unsigned int* __restrict__ hist_part, float* __restrict__ col_part,
    int nsuper, int nchunks)
{
    __shared__ unsigned int lhist[64];
    __shared__ float lcol[64];
    const int tid = threadIdx.x;
    if (tid < 64) { lhist[tid] = 0u; lcol[tid] = 0.0f; }
    __syncthreads();

    const int lane  = tid & 63;
    const int wid   = tid >> 6;
    const int gwave = blockIdx.x * (TPB / 64) + wid;
    const int nwav  = gridDim.x * (TPB / 64);
    const int sub   = lane & 15;
    const unsigned long long gm = 0xFFFFull << ((lane >> 4) << 4);

    const float K1 = 0.62011450695827756f;   // 1 + log1p(e^-1) - ln2

    float a0 = 0.f, a1 = 0.f, a2 = 0.f, a3 = 0.f;

#define PROC(P, G)                                                          \
    do {                                                                    \
        unsigned long long bx = __ballot((P).x != (G).x);                   \
        unsigned long long by = __ballot((P).y != (G).y);                   \
        unsigned long long bz = __ballot((P).z != (G).z);                   \
        unsigned long long bw = __ballot((P).w != (G).w);                   \
        a0 = fmaf((P).x, K1 - (G).x, a0);                                   \
        a1 = fmaf((P).y, K1 - (G).y, a1);                                   \
        a2 = fmaf((P).z, K1 - (G).z, a2);                                   \
        a3 = fmaf((P).w, K1 - (G).w, a3);                                   \
        if (sub == 0) {                                                     \
            int d = __popcll(bx & gm) + __popcll(by & gm)                   \
                  + __popcll(bz & gm) + __popcll(bw & gm);                  \
            atomicAdd(&lhist[d < 63 ? d : 63], 1u);                        \
        }                                                                   \
    } while (0)

    for (int s = gwave; s < nsuper; s += nwav) {
        const int base = s * 256 + lane;            // float4 index
        const float4 p0 = pred[base      ];
        const float4 g0 = gt  [base      ];
        const float4 p1 = pred[base +  64];
        const float4 g1 = gt  [base +  64];
        const float4 p2 = pred[base + 128];
        const float4 g2 = gt  [base + 128];
        const float4 p3 = pred[base + 192];
        const float4 g3 = gt  [base + 192];
        PROC(p0, g0);
        PROC(p1, g1);
        PROC(p2, g2);
        PROC(p3, g3);
    }

    for (int c = nsuper * 4 + gwave; c < nchunks; c += nwav) {
        const int idx = c * 64 + lane;
        const float4 p = pred[idx];
        const float4 g = gt[idx];
        PROC(p, g);
    }
#undef PROC

    const int col = sub * 4;
    atomicAdd(&lcol[col + 0], a0);
    atomicAdd(&lcol[col + 1], a1);
    atomicAdd(&lcol[col + 2], a2);
    atomicAdd(&lcol[col + 3], a3);

    __syncthreads();
    if (tid < 64) {
        hist_part[blockIdx.x * 64 + tid] = lhist[tid];   // coalesced 256B store
        col_part [blockIdx.x * 64 + tid] = lcol[tid];
    }
}

// One-block reducer: fold per-block partials, compute weights, weighted mean.
__global__ __launch_bounds__(RED_TPB) void hwbce_reduce(
    const unsigned int* __restrict__ hist_part,   // [nblocks][64]
    const float* __restrict__ col_part,           // [nblocks][64]
    float* __restrict__ out, int nblocks, double n_ln2, double inv_total)
{
    __shared__ float  sh[RED_SLICES][64];
    __shared__ double sc[RED_SLICES][64];
    __shared__ double pd[64];

    const int j = threadIdx.x & 63;
    const int s = threadIdx.x >> 6;               // slice 0..15

    float  h = 0.f;
    double c = 0.0;
    for (int b = s; b < nblocks; b += RED_SLICES) {
        h += (float)hist_part[b * 64 + j];        // coalesced per slice
        c += (double)col_part[b * 64 + j];
    }
    sh[s][j] = h;
    sc[s][j] = c;
    __syncthreads();

    if (s == 0) {                                 // single wave from here
        #pragma unroll
        for (int k = 1; k < RED_SLICES; ++k) { h += sh[k][j]; c += sc[k][j]; }
        const float w = expf(3.0f * fminf(h, 0.51f - h));
        pd[j] = (double)w * (c + n_ln2);
        if (j == 0) {
            double t = 0.0;
            #pragma unroll
            for (int k = 0; k < 64; ++k) t += pd[k];
            out[0] = (float)(t * inv_total);
        }
    }
}

extern "C" void kernel_launch(void* const* d_in, const int* in_sizes, int n_in,
                              void* d_out, int out_size, void* d_ws, size_t ws_size,
                              hipStream_t stream)
{
    const float4* pred = (const float4*)d_in[0];
    const float4* gt   = (const float4*)d_in[1];
    float* out = (float*)d_out;

    unsigned int* hist_part = (unsigned int*)d_ws;
    float* col_part = (float*)((char*)d_ws + (size_t)BLOCKS * 64 * sizeof(unsigned int));

    const long total   = (long)in_sizes[0];         // N * 64
    const long nrows   = total / 64;
    const int  nchunks = (int)(nrows / 4);          // 4 rows per chunk
    const int  nsuper  = nchunks / 4;               // 16 rows per superchunk

    const double n_ln2 = (double)nrows * 0.69314718055994530942;

    hwbce_main<<<BLOCKS, TPB, 0, stream>>>(pred, gt, hist_part, col_part,
                                           nsuper, nchunks);
    hwbce_reduce<<<1, RED_TPB, 0, stream>>>(hist_part, col_part, out, BLOCKS,
                                            n_ln2, 1.0 / (double)total);
}

// Round 6
// 484.556 us; speedup vs baseline: 1.1342x; 1.1342x over previous
//
#include <hip/hip_runtime.h>

#define BLOCKS 2048
#define TPB 256

typedef float nfloat4 __attribute__((ext_vector_type(4)));

// Main pass: per-row hamming-distance histogram + per-column BCE partial sums.
// One wave handles a SUPERCHUNK = 16 rows = 1024 floats = 4KB per array per
// iteration: 8 nontemporal dwordx4 wave-loads issued back-to-back before use.
//
// Per 4-row chunk: lane k holds floats [4*(k&15) .. +3] of row (k>>4).
// (p != g) compares double as wave ballots; row hamming distance = popcount of
// the row's 16-bit slice of the 4 ballot masks.
//
// BCE on exact {0,1} inputs: loss = ln2 + p*((1-g) + log1p(e^-1) - ln2).
// ln2*N is added per column at finalize.
//
// Delivered read rate here (~3.3 TB/s) matches the measured platform copy
// read-side ceiling (m13: 6.29 TB/s r+w); per-CU pending-miss concurrency is
// the wall, so the tail uses cheap global atomics (R3-proven) rather than a
// reducer kernel (R4 regression).
__global__ __launch_bounds__(TPB) void hwbce_main(
    const nfloat4* __restrict__ pred, const nfloat4* __restrict__ gt,
    unsigned int* __restrict__ g_hist, float* __restrict__ g_col,
    int nsuper, int nchunks)
{
    __shared__ unsigned int lhist[64];
    __shared__ float lcol[64];
    const int tid = threadIdx.x;
    if (tid < 64) { lhist[tid] = 0u; lcol[tid] = 0.0f; }
    __syncthreads();

    const int lane  = tid & 63;
    const int wid   = tid >> 6;
    const int gwave = blockIdx.x * (TPB / 64) + wid;
    const int nwav  = gridDim.x * (TPB / 64);
    const int sub   = lane & 15;
    const unsigned long long gm = 0xFFFFull << ((lane >> 4) << 4);

    const float K1 = 0.62011450695827756f;   // 1 + log1p(e^-1) - ln2

    float a0 = 0.f, a1 = 0.f, a2 = 0.f, a3 = 0.f;

#define PROC(P, G)                                                          \
    do {                                                                    \
        unsigned long long bx = __ballot((P).x != (G).x);                   \
        unsigned long long by = __ballot((P).y != (G).y);                   \
        unsigned long long bz = __ballot((P).z != (G).z);                   \
        unsigned long long bw = __ballot((P).w != (G).w);                   \
        a0 = fmaf((P).x, K1 - (G).x, a0);                                   \
        a1 = fmaf((P).y, K1 - (G).y, a1);                                   \
        a2 = fmaf((P).z, K1 - (G).z, a2);                                   \
        a3 = fmaf((P).w, K1 - (G).w, a3);                                   \
        if (sub == 0) {                                                     \
            int d = __popcll(bx & gm) + __popcll(by & gm)                   \
                  + __popcll(bz & gm) + __popcll(bw & gm);                  \
            atomicAdd(&lhist[d < 63 ? d : 63], 1u);                        \
        }                                                                   \
    } while (0)

    for (int s = gwave; s < nsuper; s += nwav) {
        const int base = s * 256 + lane;            // float4 index
        const nfloat4 p0 = __builtin_nontemporal_load(&pred[base      ]);
        const nfloat4 g0 = __builtin_nontemporal_load(&gt  [base      ]);
        const nfloat4 p1 = __builtin_nontemporal_load(&pred[base +  64]);
        const nfloat4 g1 = __builtin_nontemporal_load(&gt  [base +  64]);
        const nfloat4 p2 = __builtin_nontemporal_load(&pred[base + 128]);
        const nfloat4 g2 = __builtin_nontemporal_load(&gt  [base + 128]);
        const nfloat4 p3 = __builtin_nontemporal_load(&pred[base + 192]);
        const nfloat4 g3 = __builtin_nontemporal_load(&gt  [base + 192]);
        PROC(p0, g0);
        PROC(p1, g1);
        PROC(p2, g2);
        PROC(p3, g3);
    }

    for (int c = nsuper * 4 + gwave; c < nchunks; c += nwav) {
        const int idx = c * 64 + lane;
        const nfloat4 p = __builtin_nontemporal_load(&pred[idx]);
        const nfloat4 g = __builtin_nontemporal_load(&gt[idx]);
        PROC(p, g);
    }
#undef PROC

    const int col = sub * 4;
    atomicAdd(&lcol[col + 0], a0);
    atomicAdd(&lcol[col + 1], a1);
    atomicAdd(&lcol[col + 2], a2);
    atomicAdd(&lcol[col + 3], a3);

    __syncthreads();
    if (tid < 64) {
        if (lhist[tid]) atomicAdd(&g_hist[tid], lhist[tid]);
        atomicAdd(&g_col[tid], lcol[tid]);
    }
}

// Finalize: weights from histogram, weighted sum of (column sums + N*ln2), mean.
__global__ void hwbce_final(const unsigned int* __restrict__ g_hist,
                            const float* __restrict__ g_col,
                            float* __restrict__ out,
                            float n_ln2, float inv_total)
{
    __shared__ double partial[64];
    const int j = threadIdx.x;                      // 64 threads
    const float h = (float)g_hist[j];
    const float w = expf(3.0f * fminf(h, 0.51f - h));
    partial[j] = (double)w * ((double)g_col[j] + (double)n_ln2);
    __syncthreads();
    if (j == 0) {
        double s = 0.0;
        #pragma unroll
        for (int k = 0; k < 64; ++k) s += partial[k];
        out[0] = (float)(s * (double)inv_total);
    }
}

extern "C" void kernel_launch(void* const* d_in, const int* in_sizes, int n_in,
                              void* d_out, int out_size, void* d_ws, size_t ws_size,
                              hipStream_t stream)
{
    const nfloat4* pred = (const nfloat4*)d_in[0];
    const nfloat4* gt   = (const nfloat4*)d_in[1];
    float* out = (float*)d_out;

    unsigned int* g_hist = (unsigned int*)d_ws;
    float* g_col = (float*)((char*)d_ws + 64 * sizeof(unsigned int));

    const long total   = (long)in_sizes[0];         // N * 64
    const long nrows   = total / 64;
    const int  nchunks = (int)(nrows / 4);          // 4 rows per chunk
    const int  nsuper  = nchunks / 4;               // 16 rows per superchunk

    const float n_ln2 = (float)((double)nrows * 0.69314718055994530942);

    (void)hipMemsetAsync(d_ws, 0, 64 * (sizeof(unsigned int) + sizeof(float)), stream);
    hwbce_main<<<BLOCKS, TPB, 0, stream>>>(pred, gt, g_hist, g_col, nsuper, nchunks);
    hwbce_final<<<1, 64, 0, stream>>>(g_hist, g_col, out, n_ln2, 1.0f / (float)total);
}